// Round 2
// 168.922 us; speedup vs baseline: 1.0837x; 1.0837x over previous
//
#include <hip/hip_runtime.h>
#include <hip/hip_bf16.h>

// Causal linear attention (Performer ReLU kernel) via chunked MFMA (bf16).
// B=2 L=4096 H=8 D=64 M=256 fp32 in/out. Chunk T=128, C=32, NBH=16.
// R11: R10 with the chunk_kernel K A-fragment fix (missing +quad*8 k-slice
//      offset corrupted the MFMA contraction; R9's producer had it).
//   (1) chunk_kernel: fully parallel per-chunk partials Ppart = V^T(c).Kp(c)
//       (fp32) + Zpart column sums; absorbs prep (writes VTg bf16 + Pbf).
//       512 independent blocks, no inter-chunk serialization.
//   (2) prefix_kernel: BW-bound exclusive prefix over c: S (bf16, rounded
//       once like before) and Z (fp32).
//   (3) phase3_kernel: UNCHANGED from R9.
// C/D layout (m89): col = lane&15, row = quad*4 + reg.
// ws: S bf16 16.8M | Z fp32 0.5M | VTg bf16 8.4M | Pbf 32K
//     | Ppart fp32 33.6M | Zpart fp32 0.5M  ~= 59.8 MB.

#define B_   2
#define L_   4096
#define H_   8
#define D_   64
#define M_   256
#define T_   128
#define C_   (L_ / T_)   // 32
#define NBH  (B_ * H_)   // 16
#define RATIO 0.0625f    // 1/sqrt(256) == 2^-4, exact fold into k/q staging
#define STAB  0.001f
#define SVT  136         // KpL/Am/KpT/VT row stride (272B, 16B-aligned)
#define SQS  72          // Qp stage row stride

typedef __attribute__((ext_vector_type(8))) short short8;
typedef __attribute__((ext_vector_type(4))) float floatx4;

#define MFMA16(a, b, c) __builtin_amdgcn_mfma_f32_16x16x32_bf16(a, b, c, 0, 0, 0)

__device__ inline unsigned short f2bf(float x) {
    union { float f; unsigned u; } v; v.f = x;
    unsigned r = v.u + 0x7FFF + ((v.u >> 16) & 1);
    return (unsigned short)(r >> 16);
}
__device__ inline unsigned pack2bf(float a, float b) {
    __hip_bfloat162 h = __float22bfloat162_rn(make_float2(a, b));
    unsigned u; __builtin_memcpy(&u, &h, 4);
    return u;
}
// fp32 -> bf16 frag load with RATIO pre-fold (exact: 2^-4 is exponent-only)
__device__ inline short8 ldg8_bfs(const float* p) {
    float4 a = *(const float4*)p;
    float4 b = *(const float4*)(p + 4);
    short8 r;
    r[0] = (short)f2bf(a.x * RATIO); r[1] = (short)f2bf(a.y * RATIO);
    r[2] = (short)f2bf(a.z * RATIO); r[3] = (short)f2bf(a.w * RATIO);
    r[4] = (short)f2bf(b.x * RATIO); r[5] = (short)f2bf(b.y * RATIO);
    r[6] = (short)f2bf(b.z * RATIO); r[7] = (short)f2bf(b.w * RATIO);
    return r;
}
// plain fp32 -> bf16 frag load (no ratio) -- used for proj rows
__device__ inline short8 ldg8_bf(const float* p) {
    float4 a = *(const float4*)p;
    float4 b = *(const float4*)(p + 4);
    short8 r;
    r[0] = (short)f2bf(a.x); r[1] = (short)f2bf(a.y);
    r[2] = (short)f2bf(a.z); r[3] = (short)f2bf(a.w);
    r[4] = (short)f2bf(b.x); r[5] = (short)f2bf(b.y);
    r[6] = (short)f2bf(b.z); r[7] = (short)f2bf(b.w);
    return r;
}

// ---------------- chunk_kernel: per-chunk partials, fully parallel ---------
// Grid (C_=32, NBH=16) = 512 blocks, 512 thr / 8 waves, 2 blocks/CU.
// Per block (c, bh):
//   1. build VT = V^T(c) bf16 [d][t] in LDS (absorbs prep); write VTg.
//   2. for each m-half (128): wave w produces Kp m-slice [16] for all t
//      (identical math to old scan producer: kf=ldg8_bfs(key), pf=bf16 proj),
//      stores [m][t] to KpT LDS + Zpart[m]=sum_t Kp; barrier;
//      then waves compute Ppart[d][m] = V^T . Kp for this half (fp32 out).
// No inter-chunk dependencies; the serial scan chain is gone.
__global__ __launch_bounds__(512, 2)
void chunk_kernel(const float* __restrict__ key, const float* __restrict__ val,
                  const float* __restrict__ proj,
                  unsigned short* __restrict__ VTg, unsigned short* __restrict__ Pbf,
                  float* __restrict__ Ppart, float* __restrict__ Zpart) {
    const int c = blockIdx.x, bh = blockIdx.y;
    const int b = bh / H_, h = bh % H_;
    const int tid = threadIdx.x;
    const int w = tid >> 6, lane = tid & 63;
    const int l15 = lane & 15, quad = lane >> 4;

    __shared__ __align__(16) unsigned short VT[64 * SVT];    // 17.4 KB
    __shared__ __align__(16) unsigned short KpT[128 * SVT];  // 34.8 KB (m-half)

    const size_t rowstr = H_ * D_;
    const size_t base = ((size_t)b * L_ + (size_t)c * T_) * rowstr + (size_t)h * D_;

    // ---- build VT (prep logic, 512 threads) ----
    for (int i = tid; i < T_ * 16; i += 512) {
        int t = i >> 4, d4 = (i & 15) * 4;
        float4 vv = *(const float4*)(val + base + (size_t)t * rowstr + d4);
        VT[(d4 + 0) * SVT + t] = f2bf(vv.x);
        VT[(d4 + 1) * SVT + t] = f2bf(vv.y);
        VT[(d4 + 2) * SVT + t] = f2bf(vv.z);
        VT[(d4 + 3) * SVT + t] = f2bf(vv.w);
    }
    __syncthreads();
    // VTg writeout (VT is stable for the rest of the kernel)
    unsigned short* vout = VTg + ((size_t)bh * C_ + c) * (D_ * T_);
    for (int i = tid; i < D_ * 16; i += 512) {
        int d = i >> 4, tt = (i & 15) * 8;
        *(uint4*)(vout + d * T_ + tt) = *(const uint4*)&VT[d * SVT + tt];
    }
    // Pbf (proj bf16, no ratio) -- same coverage as old prep (c==0 blocks)
    if (c == 0 && tid < 256) {
        int i = bh * 256 + tid;
        float4 pv = *(const float4*)(proj + (size_t)i * 4);
        uint2 o; o.x = pack2bf(pv.x, pv.y); o.y = pack2bf(pv.z, pv.w);
        *(uint2*)(Pbf + (size_t)i * 4) = o;
    }

    float* Pp = Ppart + ((size_t)bh * C_ + c) * (D_ * M_);

    for (int half = 0; half < 2; ++half) {
        // ---- produce Kp m-slice (16 cols) for all t=0..127 ----
        const int mrow = half * 128 + w * 16 + l15;
        short8 pf0 = ldg8_bf(proj + (size_t)mrow * D_ + quad * 8);
        short8 pf1 = ldg8_bf(proj + (size_t)mrow * D_ + 32 + quad * 8);
        if (half) __syncthreads();   // guard KpT overwrite (reads of half 0 done)
        float zp = 0.f;
#pragma unroll
        for (int rt = 0; rt < 8; ++rt) {
            const float* kr = key + base + (size_t)(rt * 16 + l15) * rowstr;
            short8 kf0 = ldg8_bfs(kr + quad * 8);        // FIX: +quad*8 k-slice
            short8 kf1 = ldg8_bfs(kr + 32 + quad * 8);   // FIX: +quad*8 k-slice
            floatx4 a = {0.f, 0.f, 0.f, 0.f};
            a = MFMA16(kf0, pf0, a);
            a = MFMA16(kf1, pf1, a);
            float k0 = fmaxf(a[0], 0.f) + STAB;
            float k1 = fmaxf(a[1], 0.f) + STAB;
            float k2 = fmaxf(a[2], 0.f) + STAB;
            float k3 = fmaxf(a[3], 0.f) + STAB;
            zp += (k0 + k1) + (k2 + k3);
            uint2 pk; pk.x = pack2bf(k0, k1); pk.y = pack2bf(k2, k3);
            *(uint2*)&KpT[(w * 16 + l15) * SVT + rt * 16 + quad * 4] = pk;
        }
        zp += __shfl_xor(zp, 16, 64);
        zp += __shfl_xor(zp, 32, 64);
        if (quad == 0)
            Zpart[((size_t)bh * C_ + c) * M_ + mrow] = zp;
        __syncthreads();             // KpT half ready

        // ---- Ppart[d][m] += V^T . Kp over this half ----
        const int dt_w = w >> 1;          // d-tile 0..3 (2 waves each)
        const int mt0 = (w & 1) * 4;      // 4 m-tiles of 16 within the half
        short8 vf[4];
#pragma unroll
        for (int k4 = 0; k4 < 4; ++k4)
            vf[k4] = *(const short8*)&VT[(dt_w * 16 + l15) * SVT + k4 * 32 + quad * 8];
#pragma unroll
        for (int mt = 0; mt < 4; ++mt) {
            floatx4 acc = {0.f, 0.f, 0.f, 0.f};
#pragma unroll
            for (int k4 = 0; k4 < 4; ++k4) {
                short8 kb = *(const short8*)&KpT[((mt0 + mt) * 16 + l15) * SVT
                                                 + k4 * 32 + quad * 8];
                acc = MFMA16(vf[k4], kb, acc);
            }
            const int mcol = half * 128 + (mt0 + mt) * 16 + l15;
#pragma unroll
            for (int r = 0; r < 4; ++r)
                Pp[(size_t)(dt_w * 16 + quad * 4 + r) * M_ + mcol] = acc[r];
        }
    }
}

// ---------------- prefix_kernel: exclusive prefix over chunks --------------
// Grid (17, NBH). g<16: 256 thr x float4 -> 1024 dm elements; thread owns 4
// adjacent (d,m) columns, streams c=0..31 (fp32 acc, store-then-add = excl).
// g==16: Z prefix (fp32), thread owns one m.
__global__ __launch_bounds__(256, 4)
void prefix_kernel(const float* __restrict__ Ppart, const float* __restrict__ Zpart,
                   unsigned short* __restrict__ S, float* __restrict__ Z) {
    const int g = blockIdx.x, bh = blockIdx.y;
    const int tid = threadIdx.x;
    if (g < 16) {
        const size_t dm = ((size_t)g * 256 + tid) * 4;
        const float* Pp = Ppart + (size_t)bh * C_ * (D_ * M_) + dm;
        unsigned short* Sp = S + (size_t)bh * C_ * (D_ * M_) + dm;
        float4 acc = make_float4(0.f, 0.f, 0.f, 0.f);
#pragma unroll 4
        for (int c = 0; c < C_; ++c) {
            float4 p = *(const float4*)(Pp + (size_t)c * (D_ * M_));
            uint2 o; o.x = pack2bf(acc.x, acc.y); o.y = pack2bf(acc.z, acc.w);
            *(uint2*)(Sp + (size_t)c * (D_ * M_)) = o;
            acc.x += p.x; acc.y += p.y; acc.z += p.z; acc.w += p.w;
        }
    } else {
        const float* Zp = Zpart + (size_t)bh * C_ * M_ + tid;
        float* Zo = Z + (size_t)bh * C_ * M_ + tid;
        float acc = 0.f;
#pragma unroll 4
        for (int c = 0; c < C_; ++c) {
            float z = Zp[(size_t)c * M_];
            Zo[(size_t)c * M_] = acc;
            acc += z;
        }
    }
}

// ---------------- Phase 3: per-chunk output via MFMA (UNCHANGED R8/R9) ----
// 512 thr / 8 waves; wave w owns output rows 16w..16w+15. m in two halves:
// fg{0,1} -> KpL half -> A += Qp.Kp^T, barrier, fg{2,3} -> second half.
// Am overlays KpL after the final A barrier. P/V frags from Pbf/VTg; q/k
// converted in-flight (ldg8_bfs, RATIO folded).
__global__ __launch_bounds__(512, 2)
void phase3_kernel(const float* __restrict__ q, const float* __restrict__ key,
                   const unsigned short* __restrict__ VTg,
                   const unsigned short* __restrict__ Pbf,
                   const unsigned short* __restrict__ S, const float* __restrict__ Z,
                   float* __restrict__ out) {
    const int c = blockIdx.x, bh = blockIdx.y;
    const int b = bh / H_, h = bh % H_;
    const int tid = threadIdx.x;
    const int w = tid >> 6, lane = tid & 63;
    const int l15 = lane & 15, quad = lane >> 4;

    __shared__ __align__(16) unsigned short KpL[T_ * SVT];     // [t][mloc]; Am overlays
    __shared__ __align__(16) unsigned short QpS[8 * 16 * SQS]; // per-wave stage

    const size_t rowstr = H_ * D_;
    const size_t base = ((size_t)b * L_ + (size_t)c * T_) * rowstr + (size_t)h * D_;
    const unsigned short* Sp = S + (size_t)(bh * C_ + c) * (M_ * D_);
    const float* Zp = Z + (size_t)(bh * C_ + c) * M_;
    const unsigned short* Vc = VTg + ((size_t)bh * C_ + c) * (D_ * T_);

    short8 qf[2], kf[2];
#pragma unroll
    for (int kk = 0; kk < 2; ++kk) {
        size_t ro = base + (size_t)(16 * w + l15) * rowstr + kk * 32 + quad * 8;
        qf[kk] = ldg8_bfs(q + ro);
        kf[kk] = ldg8_bfs(key + ro);
    }

    unsigned short* myQp = QpS + w * 16 * SQS;
    floatx4 num[4];
    floatx4 Aacc[8];
#pragma unroll
    for (int dt = 0; dt < 4; ++dt) { floatx4 z4 = {0.f,0.f,0.f,0.f}; num[dt] = z4; }
#pragma unroll
    for (int ct = 0; ct < 8; ++ct) { floatx4 z4 = {0.f,0.f,0.f,0.f}; Aacc[ct] = z4; }
    float dz[4] = {0.f, 0.f, 0.f, 0.f};

    for (int hh = 0; hh < 2; ++hh) {
        short8 qa[4];
#pragma unroll
        for (int fgl = 0; fgl < 2; ++fgl) {
            const int fg = 2 * hh + fgl;
#pragma unroll
            for (int ct = 0; ct < 4; ++ct) {
                const unsigned short* pp = Pbf + (size_t)(fg * 64 + ct * 16 + l15) * D_;
                short8 pf0 = *(const short8*)(pp + quad * 8);
                short8 pf1 = *(const short8*)(pp + 32 + quad * 8);
                floatx4 aq = {0.f, 0.f, 0.f, 0.f};
                aq = MFMA16(qf[0], pf0, aq);
                aq = MFMA16(qf[1], pf1, aq);
                floatx4 ak = {0.f, 0.f, 0.f, 0.f};
                ak = MFMA16(kf[0], pf0, ak);
                ak = MFMA16(kf[1], pf1, ak);
                const int mloc = fgl * 64 + ct * 16 + l15;
                float zv = Zp[hh * 128 + mloc];
#pragma unroll
                for (int r = 0; r < 4; ++r) {
                    float qpv = fmaxf(aq[r], 0.f) + STAB;
                    float kpv = fmaxf(ak[r], 0.f) + STAB;
                    myQp[(quad * 4 + r) * SQS + ct * 16 + l15] = f2bf(qpv);
                    KpL[(size_t)(16 * w + quad * 4 + r) * SVT + mloc] = f2bf(kpv);
                    dz[r] = fmaf(qpv, zv, dz[r]);
                }
            }
            // read back own-wave A-frags (same-wave LDS dep; no barrier)
#pragma unroll
            for (int kk = 0; kk < 2; ++kk)
                qa[fgl * 2 + kk] = *(const short8*)&myQp[l15 * SQS + kk * 32 + quad * 8];
        }
        // num += Qp . S_prefix (this m-half)
#pragma unroll
        for (int dt = 0; dt < 4; ++dt)
#pragma unroll
            for (int kc = 0; kc < 4; ++kc) {
                short8 sb = *(const short8*)(Sp + (size_t)(dt * 16 + l15) * M_
                                             + hh * 128 + kc * 32 + quad * 8);
                num[dt] = MFMA16(qa[kc], sb, num[dt]);
            }
        __syncthreads();   // KpL half complete
        // A += Qp.Kp^T over this half; causal tile-skip (wave-uniform)
#pragma unroll
        for (int ct = 0; ct < 8; ++ct) {
            if (ct <= w) {
#pragma unroll
                for (int kc = 0; kc < 4; ++kc) {
                    short8 kb = *(const short8*)&KpL[(size_t)(ct * 16 + l15) * SVT
                                                     + kc * 32 + quad * 8];
                    Aacc[ct] = MFMA16(qa[kc], kb, Aacc[ct]);
                }
            }
        }
        __syncthreads();   // A reads done (next half / Am overlay may write)
    }
#pragma unroll
    for (int r = 0; r < 4; ++r) {
        dz[r] += __shfl_xor(dz[r], 1, 64);
        dz[r] += __shfl_xor(dz[r], 2, 64);
        dz[r] += __shfl_xor(dz[r], 4, 64);
        dz[r] += __shfl_xor(dz[r], 8, 64);
    }

    // mask (exact on diagonal tile), row-sum denA, write Am (own rows, KpL overlay)
    unsigned short* AmL = KpL;
    float da[4] = {0.f, 0.f, 0.f, 0.f};
#pragma unroll
    for (int ct = 0; ct < 8; ++ct)
#pragma unroll
        for (int r = 0; r < 4; ++r) {
            float av = Aacc[ct][r];
            if (ct > w || (ct == w && l15 > quad * 4 + r)) av = 0.f;
            AmL[(size_t)(16 * w + quad * 4 + r) * SVT + ct * 16 + l15] = f2bf(av);
            da[r] += av;
        }
#pragma unroll
    for (int r = 0; r < 4; ++r) {
        da[r] += __shfl_xor(da[r], 1, 64);
        da[r] += __shfl_xor(da[r], 2, 64);
        da[r] += __shfl_xor(da[r], 4, 64);
        da[r] += __shfl_xor(da[r], 8, 64);
    }

    // num += A_masked . V  (own rows; V B-frags straight from VTg)
    for (int k4 = 0; k4 <= (w >> 1); ++k4) {
        short8 am = *(const short8*)&AmL[(size_t)(16 * w + l15) * SVT
                                         + k4 * 32 + quad * 8];
#pragma unroll
        for (int dt = 0; dt < 4; ++dt) {
            short8 vb = *(const short8*)(Vc + (size_t)(dt * 16 + l15) * T_
                                         + k4 * 32 + quad * 8);
            num[dt] = MFMA16(am, vb, num[dt]);
        }
    }

    // epilogue
#pragma unroll
    for (int r = 0; r < 4; ++r) {
        float den = da[r] + dz[r];
        if (den <= 0.f) den = 1.f;
        float inv = 1.f / den;
        int t = 16 * w + quad * 4 + r;
#pragma unroll
        for (int dt = 0; dt < 4; ++dt)
            out[base + (size_t)t * rowstr + dt * 16 + l15] = num[dt][r] * inv;
    }
}

extern "C" void kernel_launch(void* const* d_in, const int* in_sizes, int n_in,
                              void* d_out, int out_size, void* d_ws, size_t ws_size,
                              hipStream_t stream) {
    const float* q    = (const float*)d_in[0];
    const float* k    = (const float*)d_in[1];
    const float* v    = (const float*)d_in[2];
    const float* proj = (const float*)d_in[3];
    float* out = (float*)d_out;

    const size_t nS = (size_t)NBH * C_ * D_ * M_;   // 8.39M (shorts / floats)
    const size_t nZ = (size_t)NBH * C_ * M_;        // 131072
    const size_t nV = (size_t)NBH * C_ * D_ * T_;   // 4.19M shorts (VTg)
    unsigned short* S     = (unsigned short*)d_ws;
    float*          Z     = (float*)(S + nS);
    unsigned short* VTg   = (unsigned short*)(Z + nZ);
    unsigned short* Pbf   = VTg + nV;
    float*          Ppart = (float*)(Pbf + (size_t)M_ * D_);
    float*          Zpart = Ppart + nS;

    chunk_kernel<<<dim3(C_, NBH), dim3(512), 0, stream>>>(k, v, proj, VTg, Pbf, Ppart, Zpart);
    prefix_kernel<<<dim3(17, NBH), dim3(256), 0, stream>>>(Ppart, Zpart, S, Z);
    phase3_kernel<<<dim3(C_, NBH), dim3(512), 0, stream>>>(q, k, VTg, Pbf, S, Z, out);
}

// Round 4
// 157.001 us; speedup vs baseline: 1.1660x; 1.0759x over previous
//
#include <hip/hip_runtime.h>
#include <hip/hip_bf16.h>

// Causal linear attention (Performer ReLU kernel) via chunked MFMA (bf16).
// B=2 L=4096 H=8 D=64 M=256 fp32 in/out. Chunk T=128, C=32, NBH=16.
// R13: R12 with the VTg frag-linear writeout loop-bound fix (covered only
//      512 of 1024 slots -> half of V^T garbage -> absmax 0.29).
//   (1) chunk_kernel: stages K once in LDS (frag-linear, conflict-free b128);
//       per-chunk partials Ppart = V^T(c).Kp(c) (fp32) + Zpart; writes VTg
//       (frag-linear bf16) + Pbf. 512 independent blocks.
//   (2) prefix_kernel: BW-bound exclusive prefix over c: S bf16, Z fp32.
//   (3) phase3_kernel: R9 structure; Vc reads use frag-linear VTg layout.
// C/D layout (m89): col = lane&15, row = quad*4 + reg.
// ws: S bf16 16.8M | Z fp32 0.5M | VTg bf16 8.4M | Pbf 32K
//     | Ppart fp32 33.6M | Zpart fp32 0.5M  ~= 59.8 MB.

#define B_   2
#define L_   4096
#define H_   8
#define D_   64
#define M_   256
#define T_   128
#define C_   (L_ / T_)   // 32
#define NBH  (B_ * H_)   // 16
#define RATIO 0.0625f    // 1/sqrt(256) == 2^-4, exact fold into k/q staging
#define STAB  0.001f
#define SVT  136         // KpL/Am/KpT/VT row stride (272B, 16B-aligned)
#define SQS  72          // Qp stage row stride

typedef __attribute__((ext_vector_type(8))) short short8;
typedef __attribute__((ext_vector_type(4))) float floatx4;

#define MFMA16(a, b, c) __builtin_amdgcn_mfma_f32_16x16x32_bf16(a, b, c, 0, 0, 0)

__device__ inline unsigned short f2bf(float x) {
    union { float f; unsigned u; } v; v.f = x;
    unsigned r = v.u + 0x7FFF + ((v.u >> 16) & 1);
    return (unsigned short)(r >> 16);
}
__device__ inline unsigned pack2bf(float a, float b) {
    __hip_bfloat162 h = __float22bfloat162_rn(make_float2(a, b));
    unsigned u; __builtin_memcpy(&u, &h, 4);
    return u;
}
// fp32 -> bf16 frag load with RATIO pre-fold (exact: 2^-4 is exponent-only)
__device__ inline short8 ldg8_bfs(const float* p) {
    float4 a = *(const float4*)p;
    float4 b = *(const float4*)(p + 4);
    short8 r;
    r[0] = (short)f2bf(a.x * RATIO); r[1] = (short)f2bf(a.y * RATIO);
    r[2] = (short)f2bf(a.z * RATIO); r[3] = (short)f2bf(a.w * RATIO);
    r[4] = (short)f2bf(b.x * RATIO); r[5] = (short)f2bf(b.y * RATIO);
    r[6] = (short)f2bf(b.z * RATIO); r[7] = (short)f2bf(b.w * RATIO);
    return r;
}
// plain fp32 -> bf16 frag load (no ratio) -- used for proj rows
__device__ inline short8 ldg8_bf(const float* p) {
    float4 a = *(const float4*)p;
    float4 b = *(const float4*)(p + 4);
    short8 r;
    r[0] = (short)f2bf(a.x); r[1] = (short)f2bf(a.y);
    r[2] = (short)f2bf(a.z); r[3] = (short)f2bf(a.w);
    r[4] = (short)f2bf(b.x); r[5] = (short)f2bf(b.y);
    r[6] = (short)f2bf(b.z); r[7] = (short)f2bf(b.w);
    return r;
}

// ---------------- chunk_kernel: per-chunk partials, fully parallel ---------
// Grid (C_=32, NBH=16) = 512 blocks, 512 thr / 8 waves, 2 blocks/CU.
// Per block (c, bh):
//   0. stage Kbf = bf16(K(c)*RATIO) into LDS frag-linear [rt*2+kk][lane]:
//      slot ((rt*2+kk)*64 + quad*16 + l15) holds K[rt*16+l15][kk*32+quad*8..]
//      -- A-frag reads are contiguous conflict-free ds_read_b128.
//   1. build VT = V^T(c) bf16 [d][t] in LDS; write VTg FRAG-LINEAR:
//      slot ((dt*4+k4)*64 + quad*16 + l15) = V^T[dt*16+l15][k4*32+quad*8..].
//   2. per m-half: wave w produces Kp m-slice [16] for all t from LDS Kbf,
//      stores [m][t] to KpT + Zpart; barrier; Ppart[d][m] = V^T . Kp.
__global__ __launch_bounds__(512, 2)
void chunk_kernel(const float* __restrict__ key, const float* __restrict__ val,
                  const float* __restrict__ proj,
                  unsigned short* __restrict__ VTg, unsigned short* __restrict__ Pbf,
                  float* __restrict__ Ppart, float* __restrict__ Zpart) {
    const int c = blockIdx.x, bh = blockIdx.y;
    const int b = bh / H_, h = bh % H_;
    const int tid = threadIdx.x;
    const int w = tid >> 6, lane = tid & 63;
    const int l15 = lane & 15, quad = lane >> 4;

    __shared__ __align__(16) unsigned short VT[64 * SVT];    // 17.4 KB
    __shared__ __align__(16) unsigned short KpT[128 * SVT];  // 34.8 KB (m-half)
    __shared__ __align__(16) unsigned short KbfL[T_ * D_];   // 16 KB frag-linear

    const size_t rowstr = H_ * D_;
    const size_t base = ((size_t)b * L_ + (size_t)c * T_) * rowstr + (size_t)h * D_;

    // ---- stage Kbf frag-linear (1024 slots of 8 shorts; 2 iters) ----
    for (int i = tid; i < T_ * 8; i += 512) {
        int t = i >> 3, d8 = (i & 7) * 8;
        short8 kv = ldg8_bfs(key + base + (size_t)t * rowstr + d8);
        int rt = t >> 4, l = t & 15, kk = d8 >> 5, q = (d8 & 31) >> 3;
        *(short8*)&KbfL[((rt * 2 + kk) * 64 + q * 16 + l) << 3] = kv;
    }
    // ---- build VT (prep logic) ----
    for (int i = tid; i < T_ * 16; i += 512) {
        int t = i >> 4, d4 = (i & 15) * 4;
        float4 vv = *(const float4*)(val + base + (size_t)t * rowstr + d4);
        VT[(d4 + 0) * SVT + t] = f2bf(vv.x);
        VT[(d4 + 1) * SVT + t] = f2bf(vv.y);
        VT[(d4 + 2) * SVT + t] = f2bf(vv.z);
        VT[(d4 + 3) * SVT + t] = f2bf(vv.w);
    }
    __syncthreads();
    // VTg writeout, FRAG-LINEAR (1024 slots; d rows have 16 t-slices of 8)
    unsigned short* vout = VTg + ((size_t)bh * C_ + c) * (D_ * T_);
    for (int i = tid; i < D_ * 16; i += 512) {
        int d = i >> 4, t8 = (i & 15) * 8;                    // FIX: 16 slices
        int dt = d >> 4, l = d & 15, k4 = t8 >> 5, q = (t8 & 31) >> 3;
        *(uint4*)(vout + (((dt * 4 + k4) * 64 + q * 16 + l) << 3)) =
            *(const uint4*)&VT[d * SVT + t8];
    }
    // Pbf (proj bf16, no ratio)
    if (c == 0 && tid < 256) {
        int i = bh * 256 + tid;
        float4 pv = *(const float4*)(proj + (size_t)i * 4);
        uint2 o; o.x = pack2bf(pv.x, pv.y); o.y = pack2bf(pv.z, pv.w);
        *(uint2*)(Pbf + (size_t)i * 4) = o;
    }

    float* Pp = Ppart + ((size_t)bh * C_ + c) * (D_ * M_);

    for (int half = 0; half < 2; ++half) {
        // ---- produce Kp m-slice (16 cols) for all t=0..127, K from LDS ----
        const int mrow = half * 128 + w * 16 + l15;
        short8 pf0 = ldg8_bf(proj + (size_t)mrow * D_ + quad * 8);
        short8 pf1 = ldg8_bf(proj + (size_t)mrow * D_ + 32 + quad * 8);
        if (half) __syncthreads();   // guard KpT overwrite (reads of half 0 done)
        float zp = 0.f;
#pragma unroll
        for (int rt = 0; rt < 8; ++rt) {
            short8 kf0 = *(const short8*)&KbfL[((rt * 2 + 0) * 64 + lane) << 3];
            short8 kf1 = *(const short8*)&KbfL[((rt * 2 + 1) * 64 + lane) << 3];
            floatx4 a = {0.f, 0.f, 0.f, 0.f};
            a = MFMA16(kf0, pf0, a);
            a = MFMA16(kf1, pf1, a);
            float k0 = fmaxf(a[0], 0.f) + STAB;
            float k1 = fmaxf(a[1], 0.f) + STAB;
            float k2 = fmaxf(a[2], 0.f) + STAB;
            float k3 = fmaxf(a[3], 0.f) + STAB;
            zp += (k0 + k1) + (k2 + k3);
            uint2 pk; pk.x = pack2bf(k0, k1); pk.y = pack2bf(k2, k3);
            *(uint2*)&KpT[(w * 16 + l15) * SVT + rt * 16 + quad * 4] = pk;
        }
        zp += __shfl_xor(zp, 16, 64);
        zp += __shfl_xor(zp, 32, 64);
        if (quad == 0)
            Zpart[((size_t)bh * C_ + c) * M_ + mrow] = zp;
        __syncthreads();             // KpT half ready

        // ---- Ppart[d][m] += V^T . Kp over this half ----
        const int dt_w = w >> 1;          // d-tile 0..3 (2 waves each)
        const int mt0 = (w & 1) * 4;      // 4 m-tiles of 16 within the half
        short8 vf[4];
#pragma unroll
        for (int k4 = 0; k4 < 4; ++k4)
            vf[k4] = *(const short8*)&VT[(dt_w * 16 + l15) * SVT + k4 * 32 + quad * 8];
#pragma unroll
        for (int mt = 0; mt < 4; ++mt) {
            floatx4 acc = {0.f, 0.f, 0.f, 0.f};
#pragma unroll
            for (int k4 = 0; k4 < 4; ++k4) {
                short8 kb = *(const short8*)&KpT[((mt0 + mt) * 16 + l15) * SVT
                                                 + k4 * 32 + quad * 8];
                acc = MFMA16(vf[k4], kb, acc);
            }
            const int mcol = half * 128 + (mt0 + mt) * 16 + l15;
#pragma unroll
            for (int r = 0; r < 4; ++r)
                Pp[(size_t)(dt_w * 16 + quad * 4 + r) * M_ + mcol] = acc[r];
        }
    }
}

// ---------------- prefix_kernel: exclusive prefix over chunks --------------
// Grid (17, NBH). g<16: 256 thr x float4 -> 1024 dm elements; thread owns 4
// adjacent (d,m) columns, streams c=0..31 (fp32 acc, store-then-add = excl).
// g==16: Z prefix (fp32), thread owns one m.
__global__ __launch_bounds__(256, 4)
void prefix_kernel(const float* __restrict__ Ppart, const float* __restrict__ Zpart,
                   unsigned short* __restrict__ S, float* __restrict__ Z) {
    const int g = blockIdx.x, bh = blockIdx.y;
    const int tid = threadIdx.x;
    if (g < 16) {
        const size_t dm = ((size_t)g * 256 + tid) * 4;
        const float* Pp = Ppart + (size_t)bh * C_ * (D_ * M_) + dm;
        unsigned short* Sp = S + (size_t)bh * C_ * (D_ * M_) + dm;
        float4 acc = make_float4(0.f, 0.f, 0.f, 0.f);
#pragma unroll 8
        for (int c = 0; c < C_; ++c) {
            float4 p = *(const float4*)(Pp + (size_t)c * (D_ * M_));
            uint2 o; o.x = pack2bf(acc.x, acc.y); o.y = pack2bf(acc.z, acc.w);
            *(uint2*)(Sp + (size_t)c * (D_ * M_)) = o;
            acc.x += p.x; acc.y += p.y; acc.z += p.z; acc.w += p.w;
        }
    } else {
        const float* Zp = Zpart + (size_t)bh * C_ * M_ + tid;
        float* Zo = Z + (size_t)bh * C_ * M_ + tid;
        float acc = 0.f;
#pragma unroll 8
        for (int c = 0; c < C_; ++c) {
            float z = Zp[(size_t)c * M_];
            Zo[(size_t)c * M_] = acc;
            acc += z;
        }
    }
}

// ---------------- Phase 3: per-chunk output via MFMA (R9 structure) -------
// 512 thr / 8 waves; wave w owns output rows 16w..16w+15. m in two halves:
// fg{0,1} -> KpL half -> A += Qp.Kp^T, barrier, fg{2,3} -> second half.
// Am overlays KpL after the final A barrier. P frags from Pbf; V B-frags
// from FRAG-LINEAR VTg (contiguous 1KB wave-loads); q/k converted in-flight.
__global__ __launch_bounds__(512, 2)
void phase3_kernel(const float* __restrict__ q, const float* __restrict__ key,
                   const unsigned short* __restrict__ VTg,
                   const unsigned short* __restrict__ Pbf,
                   const unsigned short* __restrict__ S, const float* __restrict__ Z,
                   float* __restrict__ out) {
    const int c = blockIdx.x, bh = blockIdx.y;
    const int b = bh / H_, h = bh % H_;
    const int tid = threadIdx.x;
    const int w = tid >> 6, lane = tid & 63;
    const int l15 = lane & 15, quad = lane >> 4;

    __shared__ __align__(16) unsigned short KpL[T_ * SVT];     // [t][mloc]; Am overlays
    __shared__ __align__(16) unsigned short QpS[8 * 16 * SQS]; // per-wave stage

    const size_t rowstr = H_ * D_;
    const size_t base = ((size_t)b * L_ + (size_t)c * T_) * rowstr + (size_t)h * D_;
    const unsigned short* Sp = S + (size_t)(bh * C_ + c) * (M_ * D_);
    const float* Zp = Z + (size_t)(bh * C_ + c) * M_;
    const unsigned short* Vc = VTg + ((size_t)bh * C_ + c) * (D_ * T_);

    short8 qf[2], kf[2];
#pragma unroll
    for (int kk = 0; kk < 2; ++kk) {
        size_t ro = base + (size_t)(16 * w + l15) * rowstr + kk * 32 + quad * 8;
        qf[kk] = ldg8_bfs(q + ro);
        kf[kk] = ldg8_bfs(key + ro);
    }

    unsigned short* myQp = QpS + w * 16 * SQS;
    floatx4 num[4];
    floatx4 Aacc[8];
#pragma unroll
    for (int dt = 0; dt < 4; ++dt) { floatx4 z4 = {0.f,0.f,0.f,0.f}; num[dt] = z4; }
#pragma unroll
    for (int ct = 0; ct < 8; ++ct) { floatx4 z4 = {0.f,0.f,0.f,0.f}; Aacc[ct] = z4; }
    float dz[4] = {0.f, 0.f, 0.f, 0.f};

    for (int hh = 0; hh < 2; ++hh) {
        short8 qa[4];
#pragma unroll
        for (int fgl = 0; fgl < 2; ++fgl) {
            const int fg = 2 * hh + fgl;
#pragma unroll
            for (int ct = 0; ct < 4; ++ct) {
                const unsigned short* pp = Pbf + (size_t)(fg * 64 + ct * 16 + l15) * D_;
                short8 pf0 = *(const short8*)(pp + quad * 8);
                short8 pf1 = *(const short8*)(pp + 32 + quad * 8);
                floatx4 aq = {0.f, 0.f, 0.f, 0.f};
                aq = MFMA16(qf[0], pf0, aq);
                aq = MFMA16(qf[1], pf1, aq);
                floatx4 ak = {0.f, 0.f, 0.f, 0.f};
                ak = MFMA16(kf[0], pf0, ak);
                ak = MFMA16(kf[1], pf1, ak);
                const int mloc = fgl * 64 + ct * 16 + l15;
                float zv = Zp[hh * 128 + mloc];
#pragma unroll
                for (int r = 0; r < 4; ++r) {
                    float qpv = fmaxf(aq[r], 0.f) + STAB;
                    float kpv = fmaxf(ak[r], 0.f) + STAB;
                    myQp[(quad * 4 + r) * SQS + ct * 16 + l15] = f2bf(qpv);
                    KpL[(size_t)(16 * w + quad * 4 + r) * SVT + mloc] = f2bf(kpv);
                    dz[r] = fmaf(qpv, zv, dz[r]);
                }
            }
            // read back own-wave A-frags (same-wave LDS dep; no barrier)
#pragma unroll
            for (int kk = 0; kk < 2; ++kk)
                qa[fgl * 2 + kk] = *(const short8*)&myQp[l15 * SQS + kk * 32 + quad * 8];
        }
        // num += Qp . S_prefix (this m-half)
#pragma unroll
        for (int dt = 0; dt < 4; ++dt)
#pragma unroll
            for (int kc = 0; kc < 4; ++kc) {
                short8 sb = *(const short8*)(Sp + (size_t)(dt * 16 + l15) * M_
                                             + hh * 128 + kc * 32 + quad * 8);
                num[dt] = MFMA16(qa[kc], sb, num[dt]);
            }
        __syncthreads();   // KpL half complete
        // A += Qp.Kp^T over this half; causal tile-skip (wave-uniform)
#pragma unroll
        for (int ct = 0; ct < 8; ++ct) {
            if (ct <= w) {
#pragma unroll
                for (int kc = 0; kc < 4; ++kc) {
                    short8 kb = *(const short8*)&KpL[(size_t)(ct * 16 + l15) * SVT
                                                     + kc * 32 + quad * 8];
                    Aacc[ct] = MFMA16(qa[kc], kb, Aacc[ct]);
                }
            }
        }
        __syncthreads();   // A reads done (next half / Am overlay may write)
    }
#pragma unroll
    for (int r = 0; r < 4; ++r) {
        dz[r] += __shfl_xor(dz[r], 1, 64);
        dz[r] += __shfl_xor(dz[r], 2, 64);
        dz[r] += __shfl_xor(dz[r], 4, 64);
        dz[r] += __shfl_xor(dz[r], 8, 64);
    }

    // mask (exact on diagonal tile), row-sum denA, write Am (own rows, KpL overlay)
    unsigned short* AmL = KpL;
    float da[4] = {0.f, 0.f, 0.f, 0.f};
#pragma unroll
    for (int ct = 0; ct < 8; ++ct)
#pragma unroll
        for (int r = 0; r < 4; ++r) {
            float av = Aacc[ct][r];
            if (ct > w || (ct == w && l15 > quad * 4 + r)) av = 0.f;
            AmL[(size_t)(16 * w + quad * 4 + r) * SVT + ct * 16 + l15] = f2bf(av);
            da[r] += av;
        }
#pragma unroll
    for (int r = 0; r < 4; ++r) {
        da[r] += __shfl_xor(da[r], 1, 64);
        da[r] += __shfl_xor(da[r], 2, 64);
        da[r] += __shfl_xor(da[r], 4, 64);
        da[r] += __shfl_xor(da[r], 8, 64);
    }

    // num += A_masked . V  (own rows; V B-frags from frag-linear VTg)
    for (int k4 = 0; k4 <= (w >> 1); ++k4) {
        short8 am = *(const short8*)&AmL[(size_t)(16 * w + l15) * SVT
                                         + k4 * 32 + quad * 8];
#pragma unroll
        for (int dt = 0; dt < 4; ++dt) {
            short8 vb = *(const short8*)(Vc + (((size_t)(dt * 4 + k4) * 64 + lane) << 3));
            num[dt] = MFMA16(am, vb, num[dt]);
        }
    }

    // epilogue
#pragma unroll
    for (int r = 0; r < 4; ++r) {
        float den = da[r] + dz[r];
        if (den <= 0.f) den = 1.f;
        float inv = 1.f / den;
        int t = 16 * w + quad * 4 + r;
#pragma unroll
        for (int dt = 0; dt < 4; ++dt)
            out[base + (size_t)t * rowstr + dt * 16 + l15] = num[dt][r] * inv;
    }
}

extern "C" void kernel_launch(void* const* d_in, const int* in_sizes, int n_in,
                              void* d_out, int out_size, void* d_ws, size_t ws_size,
                              hipStream_t stream) {
    const float* q    = (const float*)d_in[0];
    const float* k    = (const float*)d_in[1];
    const float* v    = (const float*)d_in[2];
    const float* proj = (const float*)d_in[3];
    float* out = (float*)d_out;

    const size_t nS = (size_t)NBH * C_ * D_ * M_;   // 8.39M (shorts / floats)
    const size_t nZ = (size_t)NBH * C_ * M_;        // 131072
    const size_t nV = (size_t)NBH * C_ * D_ * T_;   // 4.19M shorts (VTg)
    unsigned short* S     = (unsigned short*)d_ws;
    float*          Z     = (float*)(S + nS);
    unsigned short* VTg   = (unsigned short*)(Z + nZ);
    unsigned short* Pbf   = VTg + nV;
    float*          Ppart = (float*)(Pbf + (size_t)M_ * D_);
    float*          Zpart = Ppart + nS;

    chunk_kernel<<<dim3(C_, NBH), dim3(512), 0, stream>>>(k, v, proj, VTg, Pbf, Ppart, Zpart);
    prefix_kernel<<<dim3(17, NBH), dim3(256), 0, stream>>>(Ppart, Zpart, S, Z);
    phase3_kernel<<<dim3(C_, NBH), dim3(512), 0, stream>>>(q, k, VTg, Pbf, S, Z, out);
}